// Round 2
// baseline (241.902 us; speedup 1.0000x reference)
//
#include <hip/hip_runtime.h>
#include <hip/hip_bf16.h>

// Problem constants
// B=16, T_EN=256, T_DE=256, D_EN=D_DE=512, UNITS=128
// rows R = B*T = 4096 for both en and de projections.

__device__ __forceinline__ float tanh_fast(float x) {
    float ax = __builtin_fabsf(x);
    float e  = __expf(-2.0f * ax);                 // v_mul + v_exp_f32
    float r  = __builtin_amdgcn_rcpf(1.0f + e);    // approx rcp, ~1e-6 rel err
    float t  = (1.0f - e) * r;
    return __builtin_copysignf(t, x);
}

// ---------------- K1: X (4096 x 512) @ W (512 x 128) -> OUT (4096 x 128) ----
__global__ __launch_bounds__(256) void proj_kernel(
        const float* __restrict__ X, const float* __restrict__ W,
        float* __restrict__ OUT) {
    __shared__ float w_sh[64][128];   // 32 KB k-tile of W
    __shared__ float x_sh[16][64];    // 4 KB row-tile of X
    const int tid  = threadIdx.x;
    const int u    = tid & 127;       // output column
    const int half = tid >> 7;        // 0/1 -> owns rows half*8 .. +8
    const int row0 = blockIdx.x * 16;

    float acc[8];
#pragma unroll
    for (int r = 0; r < 8; ++r) acc[r] = 0.0f;

    for (int kt = 0; kt < 512; kt += 64) {
#pragma unroll
        for (int t = tid; t < 64 * 128; t += 256) {
            int kk = t >> 7, uu = t & 127;
            w_sh[kk][uu] = W[(kt + kk) * 128 + uu];
        }
#pragma unroll
        for (int t = tid; t < 16 * 64; t += 256) {
            int r = t >> 6, kk = t & 63;
            x_sh[r][kk] = X[(row0 + r) * 512 + kt + kk];
        }
        __syncthreads();
#pragma unroll 16
        for (int kk = 0; kk < 64; ++kk) {
            float wv = w_sh[kk][u];
#pragma unroll
            for (int r = 0; r < 8; ++r)
                acc[r] = fmaf(x_sh[half * 8 + r][kk], wv, acc[r]);
        }
        __syncthreads();
    }
#pragma unroll
    for (int r = 0; r < 8; ++r)
        OUT[(row0 + half * 8 + r) * 128 + u] = acc[r];
}

// ---------------- K2: mu + softmax -> alphas (4096 x 256) -------------------
// One block per (b,j). Thread tid = encoder index i (0..255).
__global__ __launch_bounds__(256) void mu_softmax_kernel(
        const float* __restrict__ att_en, const float* __restrict__ att_de,
        const float* __restrict__ nu, float* __restrict__ alphas) {
    const int tid = threadIdx.x;         // i
    const int bj  = blockIdx.x;          // b*256 + j
    const int b   = bj >> 8;

    __shared__ float de_sh[128];
    __shared__ float nu_sh[128];
    __shared__ float red_m[4];
    __shared__ float red_s[4];

    if (tid < 128) {
        de_sh[tid] = att_de[bj * 128 + tid];
        nu_sh[tid] = nu[tid];
    }
    __syncthreads();

    const float4* enrow =
        reinterpret_cast<const float4*>(att_en + (size_t)(b * 256 + tid) * 128);
    float s = 0.0f;
#pragma unroll 8
    for (int q = 0; q < 32; ++q) {
        float4 a = enrow[q];
        float x0 = a.x + de_sh[q * 4 + 0];
        float x1 = a.y + de_sh[q * 4 + 1];
        float x2 = a.z + de_sh[q * 4 + 2];
        float x3 = a.w + de_sh[q * 4 + 3];
        s = fmaf(tanh_fast(x0), nu_sh[q * 4 + 0], s);
        s = fmaf(tanh_fast(x1), nu_sh[q * 4 + 1], s);
        s = fmaf(tanh_fast(x2), nu_sh[q * 4 + 2], s);
        s = fmaf(tanh_fast(x3), nu_sh[q * 4 + 3], s);
    }

    // block-wide softmax over 256 values (4 waves)
    const int lane = tid & 63, wv = tid >> 6;
    float m = s;
#pragma unroll
    for (int off = 32; off >= 1; off >>= 1) m = fmaxf(m, __shfl_xor(m, off));
    if (lane == 0) red_m[wv] = m;
    __syncthreads();
    m = fmaxf(fmaxf(red_m[0], red_m[1]), fmaxf(red_m[2], red_m[3]));

    float p = __expf(s - m);
    float t = p;
#pragma unroll
    for (int off = 32; off >= 1; off >>= 1) t += __shfl_xor(t, off);
    if (lane == 0) red_s[wv] = t;
    __syncthreads();
    float tot = red_s[0] + red_s[1] + red_s[2] + red_s[3];

    alphas[(size_t)bj * 256 + tid] = p * __builtin_amdgcn_rcpf(tot);
}

// ---------------- K3: out = [de_seq | alphas @ en_seq] ----------------------
// Block handles (b, 8 j-rows). Thread tid owns output columns tid, tid+256.
__global__ __launch_bounds__(256) void pv_kernel(
        const float* __restrict__ alphas, const float* __restrict__ en,
        const float* __restrict__ de, float* __restrict__ out) {
    const int tid = threadIdx.x;
    const int b   = blockIdx.y;
    const int j0  = blockIdx.x * 8;

    __shared__ float al[8][256];   // 8 KB
#pragma unroll
    for (int t = tid; t < 8 * 256; t += 256) {
        int j = t >> 8, i = t & 255;
        al[j][i] = alphas[(size_t)(b * 256 + j0 + j) * 256 + i];
    }
    // fused de_seq copy into the left half of out
#pragma unroll
    for (int j = 0; j < 8; ++j) {
        size_t row = (size_t)(b * 256 + j0 + j);
        out[row * 1024 + tid]       = de[row * 512 + tid];
        out[row * 1024 + tid + 256] = de[row * 512 + tid + 256];
    }
    __syncthreads();

    float acc0[8], acc1[8];
#pragma unroll
    for (int j = 0; j < 8; ++j) { acc0[j] = 0.0f; acc1[j] = 0.0f; }

    const float* enb = en + (size_t)b * 256 * 512;
#pragma unroll 4
    for (int i = 0; i < 256; ++i) {
        float e0 = enb[i * 512 + tid];
        float e1 = enb[i * 512 + tid + 256];
#pragma unroll
        for (int j = 0; j < 8; ++j) {
            float a = al[j][i];
            acc0[j] = fmaf(a, e0, acc0[j]);
            acc1[j] = fmaf(a, e1, acc1[j]);
        }
    }
#pragma unroll
    for (int j = 0; j < 8; ++j) {
        size_t row = (size_t)(b * 256 + j0 + j);
        out[row * 1024 + 512 + tid] = acc0[j];
        out[row * 1024 + 768 + tid] = acc1[j];
    }
}

extern "C" void kernel_launch(void* const* d_in, const int* in_sizes, int n_in,
                              void* d_out, int out_size, void* d_ws, size_t ws_size,
                              hipStream_t stream) {
    const float* en   = (const float*)d_in[0];  // (16,256,512)
    const float* de   = (const float*)d_in[1];  // (16,256,512)
    const float* w_en = (const float*)d_in[2];  // (512,128)
    const float* w_de = (const float*)d_in[3];  // (512,128)
    const float* nu   = (const float*)d_in[4];  // (128,1)
    float* out = (float*)d_out;                 // (16,256,1024)

    char* ws = (char*)d_ws;
    float* att_en = (float*)(ws);                                   // 4096x128
    float* att_de = (float*)(ws + (size_t)4096 * 128 * 4);          // 4096x128
    float* alphas = (float*)(ws + (size_t)2 * 4096 * 128 * 4);      // 4096x256

    proj_kernel<<<dim3(256), 256, 0, stream>>>(en, w_en, att_en);
    proj_kernel<<<dim3(256), 256, 0, stream>>>(de, w_de, att_de);
    mu_softmax_kernel<<<dim3(4096), 256, 0, stream>>>(att_en, att_de, nu, alphas);
    pv_kernel<<<dim3(32, 16), 256, 0, stream>>>(alphas, en, de, out);
}

// Round 3
// 193.820 us; speedup vs baseline: 1.2481x; 1.2481x over previous
//
#include <hip/hip_runtime.h>
#include <hip/hip_bf16.h>

// B=16, T_EN=256, T_DE=256, D=512, UNITS=128
// tanh(x) = (1-e)/(1+e), e = 2^(-(2/ln2)*x)  -- valid for both signs.
// Projections write att * (2/ln2) so phase A needs no extra multiply.
#define TANH_SCALE 2.8853900817779268f   // 2/ln(2)

// ---------------- K1: dual projection -----------------------------------
// grid (256, 2): y=0 -> en @ w_en -> att_en ; y=1 -> de @ w_de -> att_de
// block: 256 threads, 16 rows x 128 cols; u=tid&127, half owns 8 rows.
__global__ __launch_bounds__(256, 2) void proj2_kernel(
        const float* __restrict__ en, const float* __restrict__ de,
        const float* __restrict__ w_en, const float* __restrict__ w_de,
        float* __restrict__ att_en, float* __restrict__ att_de) {
    const float* X;
    const float* W;
    float* OUT;
    if (blockIdx.y == 0) { X = en; W = w_en; OUT = att_en; }
    else                 { X = de; W = w_de; OUT = att_de; }

    __shared__ float w_sh[64][128];   // 32 KB k-tile of W
    __shared__ float x_sh[16][64];    // 4 KB row-tile of X
    const int tid  = threadIdx.x;
    const int u    = tid & 127;
    const int half = tid >> 7;
    const int row0 = blockIdx.x * 16;

    float acc[8];
#pragma unroll
    for (int r = 0; r < 8; ++r) acc[r] = 0.0f;

    for (int kt = 0; kt < 512; kt += 64) {
        // stage W k-tile: 2048 float4, 8 per thread (coalesced)
        const float4* Wg = reinterpret_cast<const float4*>(W + (size_t)kt * 128);
        float4* wsh4 = reinterpret_cast<float4*>(&w_sh[0][0]);
#pragma unroll
        for (int t = 0; t < 8; ++t) wsh4[tid + 256 * t] = Wg[tid + 256 * t];
        // stage X tile: 256 float4, 1 per thread
        {
            int r = tid >> 4, kk4 = (tid & 15) * 4;
            reinterpret_cast<float4*>(&x_sh[0][0])[tid] =
                *reinterpret_cast<const float4*>(X + (size_t)(row0 + r) * 512 + kt + kk4);
        }
        __syncthreads();
#pragma unroll
        for (int kk = 0; kk < 64; kk += 4) {
            float w0 = w_sh[kk][u], w1 = w_sh[kk + 1][u];
            float w2 = w_sh[kk + 2][u], w3 = w_sh[kk + 3][u];
#pragma unroll
            for (int r = 0; r < 8; ++r) {
                float4 x4 = *reinterpret_cast<const float4*>(&x_sh[half * 8 + r][kk]);
                acc[r] = fmaf(x4.x, w0, acc[r]);
                acc[r] = fmaf(x4.y, w1, acc[r]);
                acc[r] = fmaf(x4.z, w2, acc[r]);
                acc[r] = fmaf(x4.w, w3, acc[r]);
            }
        }
        __syncthreads();
    }
#pragma unroll
    for (int r = 0; r < 8; ++r)
        OUT[(size_t)(row0 + half * 8 + r) * 128 + u] = acc[r] * TANH_SCALE;
}

// ---------------- K2: fused mu + softmax + PV + de-copy -------------------
// 512 blocks (XCD-swizzled): logical id -> (b, j-tile of 8 decoder rows).
// Thread tid = encoder index i in phases A/B; = output column pair in C.
__global__ __launch_bounds__(256, 2) void fused_attn_kernel(
        const float* __restrict__ att_en, const float* __restrict__ att_de,
        const float* __restrict__ nu, const float* __restrict__ en,
        const float* __restrict__ de, float* __restrict__ out) {
    // XCD swizzle: 512 % 8 == 0; XCD k gets logical blocks [k*64, (k+1)*64)
    const int phys = blockIdx.x;
    const int lid  = (phys & 7) * 64 + (phys >> 3);
    const int b    = lid >> 5;          // 0..15
    const int j0   = (lid & 31) * 8;    // 0..248
    const int tid  = threadIdx.x;

    __shared__ float de_sh[8][128];     // 4 KB: att_de rows (pre-scaled)
    __shared__ float nu_sh[128];
    __shared__ float al[8][256];        // 8 KB: alphas
    __shared__ float red[4][8];

    // stage att_de tile (8 rows x 128 = 256 float4, 1/thread) + nu
    reinterpret_cast<float4*>(&de_sh[0][0])[tid] =
        reinterpret_cast<const float4*>(att_de + ((size_t)b * 256 + j0) * 128)[tid];
    if (tid < 128) nu_sh[tid] = nu[tid];

    // de_seq copy into left half of out (independent; overlaps everything)
    {
        const float4* dsrc =
            reinterpret_cast<const float4*>(de + ((size_t)b * 256 + j0) * 512);
#pragma unroll
        for (int t = 0; t < 4; ++t) {
            int idx = tid + 256 * t;        // 0..1023 ; 128 float4 per row
            int j = idx >> 7, c4 = idx & 127;
            reinterpret_cast<float4*>(out + (size_t)(b * 256 + j0 + j) * 1024)[c4] =
                dsrc[idx];
        }
    }
    __syncthreads();

    // ---- phase A: s[j] = sum_u tanh(de[j][u]+en[i][u]) * nu[u], i = tid ----
    float s[8];
#pragma unroll
    for (int j = 0; j < 8; ++j) s[j] = 0.0f;
    const float4* en4 =
        reinterpret_cast<const float4*>(att_en + ((size_t)b * 256 + tid) * 128);
    for (int q = 0; q < 4; ++q) {       // 32 u per chunk
        float ev[32];
#pragma unroll
        for (int t = 0; t < 8; ++t) {
            float4 v = en4[q * 8 + t];
            ev[4 * t] = v.x; ev[4 * t + 1] = v.y;
            ev[4 * t + 2] = v.z; ev[4 * t + 3] = v.w;
        }
#pragma unroll
        for (int uu = 0; uu < 32; ++uu) {
            float nuv = nu_sh[q * 32 + uu];
#pragma unroll
            for (int j = 0; j < 8; ++j) {
                float x = ev[uu] + de_sh[j][q * 32 + uu];   // pre-scaled by 2/ln2
                float e = __builtin_exp2f(-x);
                float r = __builtin_amdgcn_rcpf(1.0f + e);
                float t = fmaf(-e, r, r);                   // (1-e)/(1+e)
                s[j] = fmaf(t, nuv, s[j]);
            }
        }
    }

    // ---- phase B: softmax over i (no max-pass: |mu| <= 28, exp safe) ----
    float p[8];
#pragma unroll
    for (int j = 0; j < 8; ++j) p[j] = __expf(s[j]);
    float tot[8];
#pragma unroll
    for (int j = 0; j < 8; ++j) {
        float t = p[j];
#pragma unroll
        for (int off = 32; off >= 1; off >>= 1) t += __shfl_xor(t, off);
        tot[j] = t;
    }
    const int lane = tid & 63, wv = tid >> 6;
    if (lane == 0) {
#pragma unroll
        for (int j = 0; j < 8; ++j) red[wv][j] = tot[j];
    }
    __syncthreads();
#pragma unroll
    for (int j = 0; j < 8; ++j) {
        float T = red[0][j] + red[1][j] + red[2][j] + red[3][j];
        al[j][tid] = p[j] * __builtin_amdgcn_rcpf(T);
    }
    __syncthreads();

    // ---- phase C: sum_en[j][c] = sum_i al[j][i] * en[b][i][c] ----
    float acc0[8], acc1[8];
#pragma unroll
    for (int j = 0; j < 8; ++j) { acc0[j] = 0.0f; acc1[j] = 0.0f; }
    const float* enb = en + (size_t)b * 256 * 512;
    for (int i0 = 0; i0 < 256; i0 += 4) {
        float a[8][4];
#pragma unroll
        for (int j = 0; j < 8; ++j) {
            float4 v = *reinterpret_cast<const float4*>(&al[j][i0]);  // broadcast
            a[j][0] = v.x; a[j][1] = v.y; a[j][2] = v.z; a[j][3] = v.w;
        }
#pragma unroll
        for (int ii = 0; ii < 4; ++ii) {
            float e0 = enb[(size_t)(i0 + ii) * 512 + tid];
            float e1 = enb[(size_t)(i0 + ii) * 512 + tid + 256];
#pragma unroll
            for (int j = 0; j < 8; ++j) {
                acc0[j] = fmaf(a[j][ii], e0, acc0[j]);
                acc1[j] = fmaf(a[j][ii], e1, acc1[j]);
            }
        }
    }
#pragma unroll
    for (int j = 0; j < 8; ++j) {
        size_t row = (size_t)(b * 256 + j0 + j);
        out[row * 1024 + 512 + tid] = acc0[j];
        out[row * 1024 + 768 + tid] = acc1[j];
    }
}

extern "C" void kernel_launch(void* const* d_in, const int* in_sizes, int n_in,
                              void* d_out, int out_size, void* d_ws, size_t ws_size,
                              hipStream_t stream) {
    const float* en   = (const float*)d_in[0];  // (16,256,512)
    const float* de   = (const float*)d_in[1];  // (16,256,512)
    const float* w_en = (const float*)d_in[2];  // (512,128)
    const float* w_de = (const float*)d_in[3];  // (512,128)
    const float* nu   = (const float*)d_in[4];  // (128,1)
    float* out = (float*)d_out;                 // (16,256,1024)

    char* ws = (char*)d_ws;
    float* att_en = (float*)(ws);                          // 4096x128 (scaled)
    float* att_de = (float*)(ws + (size_t)4096 * 128 * 4); // 4096x128 (scaled)

    proj2_kernel<<<dim3(256, 2), 256, 0, stream>>>(en, de, w_en, w_de,
                                                   att_en, att_de);
    fused_attn_kernel<<<dim3(512), 256, 0, stream>>>(att_en, att_de, nu,
                                                     en, de, out);
}

// Round 4
// 163.808 us; speedup vs baseline: 1.4767x; 1.1832x over previous
//
#include <hip/hip_runtime.h>
#include <hip/hip_bf16.h>

// B=16, T_EN=256, T_DE=256, D=512, UNITS=128
// tanh(x) = (1-e)/(1+e), e = exp(-2x) = Een*Ede where E = 2^(-(2/ln2)*att).
// nu*tanh = 2nu/(1+e) - nu ; the -nu term is constant over the softmax axis
// (encoder i) and cancels -> phase A per eval: mul, add, rcp, fma only.
#define TANH_SCALE 2.8853900817779268f   // 2/ln(2)

// ---------------- K1: E = exp2(-TANH_SCALE * (X @ W)) ----------------------
// grid (512, 2): y=0 -> en -> Een ; y=1 -> de -> Ede.  8 rows per block.
__global__ __launch_bounds__(256, 4) void proj2_kernel(
        const float* __restrict__ en, const float* __restrict__ de,
        const float* __restrict__ w_en, const float* __restrict__ w_de,
        float* __restrict__ Een, float* __restrict__ Ede) {
    const float* X;
    const float* W;
    float* OUT;
    if (blockIdx.y == 0) { X = en; W = w_en; OUT = Een; }
    else                 { X = de; W = w_de; OUT = Ede; }

    __shared__ float w_sh[64][128];   // 32 KB k-tile of W
    __shared__ float x_sh[8][64];     // 2 KB row-tile of X
    const int tid  = threadIdx.x;
    const int u    = tid & 127;
    const int half = tid >> 7;        // owns rows half*4 .. +4
    const int row0 = blockIdx.x * 8;

    float acc[4] = {0.0f, 0.0f, 0.0f, 0.0f};

    for (int kt = 0; kt < 512; kt += 64) {
        const float4* Wg = reinterpret_cast<const float4*>(W + (size_t)kt * 128);
        float4* wsh4 = reinterpret_cast<float4*>(&w_sh[0][0]);
#pragma unroll
        for (int t = 0; t < 8; ++t) wsh4[tid + 256 * t] = Wg[tid + 256 * t];
        if (tid < 128) {
            int r = tid >> 4, kk4 = (tid & 15) * 4;
            reinterpret_cast<float4*>(&x_sh[0][0])[tid] =
                *reinterpret_cast<const float4*>(X + (size_t)(row0 + r) * 512 + kt + kk4);
        }
        __syncthreads();
#pragma unroll
        for (int kk = 0; kk < 64; kk += 4) {
            float w0 = w_sh[kk][u], w1 = w_sh[kk + 1][u];
            float w2 = w_sh[kk + 2][u], w3 = w_sh[kk + 3][u];
#pragma unroll
            for (int r = 0; r < 4; ++r) {
                float4 x4 = *reinterpret_cast<const float4*>(&x_sh[half * 4 + r][kk]);
                acc[r] = fmaf(x4.x, w0, acc[r]);
                acc[r] = fmaf(x4.y, w1, acc[r]);
                acc[r] = fmaf(x4.z, w2, acc[r]);
                acc[r] = fmaf(x4.w, w3, acc[r]);
            }
        }
        __syncthreads();
    }
#pragma unroll
    for (int r = 0; r < 4; ++r)
        OUT[(size_t)(row0 + half * 4 + r) * 128 + u] =
            __builtin_exp2f(-TANH_SCALE * acc[r]);
}

// ---------------- K2: fused mu + softmax + PV + de-copy ---------------------
// 512 blocks x 512 threads. Block = (b, j-tile of 8 decoder rows).
// Phase A/B: i = tid&255, uh = tid>>8 handles j = uh*4..uh*4+3 (full u range).
// Phase C: thread owns output column c = tid (0..511).
__global__ __launch_bounds__(512, 4) void fused_attn_kernel(
        const float* __restrict__ Een, const float* __restrict__ Ede,
        const float* __restrict__ nu, const float* __restrict__ en,
        const float* __restrict__ de, float* __restrict__ out) {
    const int phys = blockIdx.x;
    const int lid  = (phys & 7) * 64 + (phys >> 3);   // XCD swizzle (512%8==0)
    const int b    = lid >> 5;          // 0..15
    const int j0   = (lid & 31) * 8;    // 0..248
    const int tid  = threadIdx.x;
    const int i    = tid & 255;
    const int uh   = tid >> 8;          // 0/1

    __shared__ float ede_sh[8][128];    // 4 KB
    __shared__ float nu2_sh[128];       // 2*nu
    __shared__ float al[8][256];        // 8 KB alphas
    __shared__ float red[8][4];         // [j][wave-in-half]

    if (tid < 256)
        reinterpret_cast<float4*>(&ede_sh[0][0])[tid] =
            reinterpret_cast<const float4*>(Ede + ((size_t)b * 256 + j0) * 128)[tid];
    if (tid >= 256 && tid < 384) nu2_sh[tid - 256] = 2.0f * nu[tid - 256];

    // de_seq copy into left half of out (overlaps everything)
    {
        const float4* dsrc =
            reinterpret_cast<const float4*>(de + ((size_t)b * 256 + j0) * 512);
#pragma unroll
        for (int t = 0; t < 2; ++t) {
            int idx = tid + 512 * t;        // 0..1023
            int j = idx >> 7, c4 = idx & 127;
            reinterpret_cast<float4*>(out + (size_t)(b * 256 + j0 + j) * 1024)[c4] =
                dsrc[idx];
        }
    }
    __syncthreads();

    // ---- phase A: s[jl] = sum_u nu2[u] / (1 + Een[i][u]*Ede[j][u]) ----
    float s[4] = {0.0f, 0.0f, 0.0f, 0.0f};
    const float4* e4 =
        reinterpret_cast<const float4*>(Een + ((size_t)b * 256 + i) * 128);
    for (int q = 0; q < 8; ++q) {       // chunks of 16 u
        float ev[16], nv[16];
#pragma unroll
        for (int t = 0; t < 4; ++t) {
            float4 a = e4[q * 4 + t];
            ev[4 * t] = a.x; ev[4 * t + 1] = a.y; ev[4 * t + 2] = a.z; ev[4 * t + 3] = a.w;
            float4 n = *reinterpret_cast<const float4*>(&nu2_sh[q * 16 + 4 * t]);
            nv[4 * t] = n.x; nv[4 * t + 1] = n.y; nv[4 * t + 2] = n.z; nv[4 * t + 3] = n.w;
        }
#pragma unroll
        for (int jl = 0; jl < 4; ++jl) {
            const int j = uh * 4 + jl;
            float dv[16];
#pragma unroll
            for (int t = 0; t < 4; ++t) {
                float4 d = *reinterpret_cast<const float4*>(&ede_sh[j][q * 16 + 4 * t]);
                dv[4 * t] = d.x; dv[4 * t + 1] = d.y; dv[4 * t + 2] = d.z; dv[4 * t + 3] = d.w;
            }
#pragma unroll
            for (int t = 0; t < 16; ++t) {
                float e = ev[t] * dv[t];
                float r = __builtin_amdgcn_rcpf(1.0f + e);
                s[jl] = fmaf(nv[t], r, s[jl]);
            }
        }
    }

    // ---- phase B: softmax over i (shift by Snu cancels; exp is safe) ----
    float p[4];
#pragma unroll
    for (int jl = 0; jl < 4; ++jl) p[jl] = __expf(s[jl]);
    const int lane = tid & 63;
    const int w    = (tid >> 6) & 3;    // wave within half
#pragma unroll
    for (int jl = 0; jl < 4; ++jl) {
        float t = p[jl];
#pragma unroll
        for (int off = 32; off >= 1; off >>= 1) t += __shfl_xor(t, off);
        if (lane == 0) red[uh * 4 + jl][w] = t;
    }
    __syncthreads();
#pragma unroll
    for (int jl = 0; jl < 4; ++jl) {
        const int j = uh * 4 + jl;
        float T = red[j][0] + red[j][1] + red[j][2] + red[j][3];
        al[j][i] = p[jl] * __builtin_amdgcn_rcpf(T);
    }
    __syncthreads();

    // ---- phase C: sum_en[j][c] = sum_i al[j][i] * en[b][i][c], c = tid ----
    float acc[8];
#pragma unroll
    for (int j = 0; j < 8; ++j) acc[j] = 0.0f;
    const float* enb = en + (size_t)b * 256 * 512;
    const int c = tid;
    for (int i0 = 0; i0 < 256; i0 += 4) {
        float a[8][4];
#pragma unroll
        for (int j = 0; j < 8; ++j) {
            float4 v = *reinterpret_cast<const float4*>(&al[j][i0]);  // broadcast
            a[j][0] = v.x; a[j][1] = v.y; a[j][2] = v.z; a[j][3] = v.w;
        }
#pragma unroll
        for (int ii = 0; ii < 4; ++ii) {
            float e0 = enb[(size_t)(i0 + ii) * 512 + c];
#pragma unroll
            for (int j = 0; j < 8; ++j)
                acc[j] = fmaf(a[j][ii], e0, acc[j]);
        }
    }
#pragma unroll
    for (int j = 0; j < 8; ++j) {
        size_t row = (size_t)(b * 256 + j0 + j);
        out[row * 1024 + 512 + c] = acc[j];
    }
}

extern "C" void kernel_launch(void* const* d_in, const int* in_sizes, int n_in,
                              void* d_out, int out_size, void* d_ws, size_t ws_size,
                              hipStream_t stream) {
    const float* en   = (const float*)d_in[0];  // (16,256,512)
    const float* de   = (const float*)d_in[1];  // (16,256,512)
    const float* w_en = (const float*)d_in[2];  // (512,128)
    const float* w_de = (const float*)d_in[3];  // (512,128)
    const float* nu   = (const float*)d_in[4];  // (128,1)
    float* out = (float*)d_out;                 // (16,256,1024)

    char* ws = (char*)d_ws;
    float* Een = (float*)(ws);                          // 4096x128  2^(-s*att_en)
    float* Ede = (float*)(ws + (size_t)4096 * 128 * 4); // 4096x128  2^(-s*att_de)

    proj2_kernel<<<dim3(512, 2), 256, 0, stream>>>(en, de, w_en, w_de, Een, Ede);
    fused_attn_kernel<<<dim3(512), 512, 0, stream>>>(Een, Ede, nu, en, de, out);
}